// Round 5
// baseline (525.996 us; speedup 1.0000x reference)
//
#include <hip/hip_runtime.h>
#include <hip/hip_bf16.h>
#include <math.h>

// Problem constants (B=4, H=W=64, C=128, DI=256, N=16, R=8, K=4)
#define DDIM 256
#define NCH  128
#define LCH  32

typedef __attribute__((ext_vector_type(8))) short bf8_t;
typedef __attribute__((ext_vector_type(4))) float f32x4;
typedef __attribute__((ext_vector_type(8))) unsigned short u16x8;

__device__ __forceinline__ float silu_f(float x) {
    return x / (1.f + __expf(-x));
}
__device__ __forceinline__ float softplus_f(float x) {
    return fmaxf(x, 0.f) + __logf(1.f + __expf(-fabsf(x)));
}
__device__ __forceinline__ unsigned short f2b(float x) {
    union { __hip_bfloat16 h; unsigned short u; } v;
    v.h = __float2bfloat16(x);
    return v.u;
}
__device__ __forceinline__ int perm_idx(int k, int l) {
    switch (k & 3) {
        case 0: return l;
        case 1: return ((l & 63) << 6) | (l >> 6);
        case 2: return 4095 - l;
        default: { int lr = 4095 - l; return ((lr & 63) << 6) | (lr >> 6); }
    }
}
// dA[n] = e1^(n+1), log-depth mul tree
__device__ __forceinline__ void pow_geom(float e1, float dA[16]) {
    const float e2 = e1 * e1, e4 = e2 * e2, e8 = e4 * e4;
    dA[0] = e1;       dA[1] = e2;       dA[2] = e2 * e1;  dA[3] = e4;
    dA[4] = e4 * e1;  dA[5] = e4 * e2;  dA[6] = e4 * dA[2]; dA[7] = e8;
    dA[8] = e8 * e1;  dA[9] = e8 * e2;  dA[10] = e8 * dA[2]; dA[11] = e8 * e4;
    dA[12] = e8 * dA[4]; dA[13] = e8 * dA[5]; dA[14] = e8 * dA[6]; dA[15] = e8 * e8;
}
// delta = softplus(bias + dot8(proj_dt, w8)) with float4 loads
__device__ __forceinline__ float delta_of(const float* pr0, const float4 w0,
                                          const float4 w1, float bias) {
    const float4 p0 = *(const float4*)pr0;
    const float4 p1 = *(const float4*)(pr0 + 4);
    float x = bias;
    x = fmaf(p0.x, w0.x, x); x = fmaf(p0.y, w0.y, x);
    x = fmaf(p0.z, w0.z, x); x = fmaf(p0.w, w0.w, x);
    x = fmaf(p1.x, w1.x, x); x = fmaf(p1.y, w1.y, x);
    x = fmaf(p1.z, w1.z, x); x = fmaf(p1.w, w1.w, x);
    return softplus_f(x);
}
__device__ __forceinline__ bool geom_check(const float* Alogs, int kd, float& a0) {
    a0 = -__expf(Alogs[(size_t)kd * 16]);
    bool g = true;
    #pragma unroll
    for (int n = 1; n < 16; ++n) {
        const float an = -__expf(Alogs[(size_t)kd * 16 + n]);
        const float rr = a0 * (float)(n + 1);
        g = g && (fabsf(an - rr) <= 1e-4f * fabsf(rr));
    }
    return g;
}

// ---------------------------------------------------------------------------
// fp32 -> bf16 conversion (weights only)
// ---------------------------------------------------------------------------
__global__ __launch_bounds__(256) void cvt_bf16(
    const float* __restrict__ in, unsigned short* __restrict__ out, int n8) {
    const int i = blockIdx.x * 256 + threadIdx.x;
    if (i >= n8) return;
    const float4 a = ((const float4*)in)[i * 2];
    const float4 b = ((const float4*)in)[i * 2 + 1];
    u16x8 r;
    r[0] = f2b(a.x); r[1] = f2b(a.y); r[2] = f2b(a.z); r[3] = f2b(a.w);
    r[4] = f2b(b.x); r[5] = f2b(b.y); r[6] = f2b(b.z); r[7] = f2b(b.w);
    *(u16x8*)(out + (size_t)i * 8) = r;
}

// ---------------------------------------------------------------------------
// bf16 MFMA GEMM: out[m,n] = sum_k A[m,k] * W[n,k]  (W: NxK bf16)
// ---------------------------------------------------------------------------
template <int EPI, bool AF32>
__global__ __launch_bounds__(256) void gemm_bf(
    const unsigned short* __restrict__ A, const float* __restrict__ Af,
    const unsigned short* __restrict__ W,
    float* __restrict__ out0, float* __restrict__ out1, int N, int K) {
    __shared__ unsigned short As[128][40];
    __shared__ unsigned short Bs[128][40];
    const int tid = threadIdx.x;
    const int lane = tid & 63;
    const int wid = tid >> 6;
    const int wr = wid >> 1, wc = wid & 1;
    const int m0 = blockIdx.y << 7, n0 = blockIdx.x << 7;
    const int r = lane & 15, g = lane >> 4;
    f32x4 acc[4][4];
    #pragma unroll
    for (int i = 0; i < 4; ++i)
        #pragma unroll
        for (int j = 0; j < 4; ++j) acc[i][j] = (f32x4){0.f, 0.f, 0.f, 0.f};
    const int row0 = tid >> 2;       // 0..63
    const int cc = (tid & 3) << 3;   // 0,8,16,24

    for (int k0 = 0; k0 < K; k0 += 32) {
        #pragma unroll
        for (int h = 0; h < 2; ++h) {
            const int row = row0 + (h << 6);
            u16x8 va;
            if (AF32) {
                const float* ap = Af + (size_t)(m0 + row) * K + k0 + cc;
                const float4 a0 = *(const float4*)ap;
                const float4 a1 = *(const float4*)(ap + 4);
                va[0] = f2b(a0.x); va[1] = f2b(a0.y);
                va[2] = f2b(a0.z); va[3] = f2b(a0.w);
                va[4] = f2b(a1.x); va[5] = f2b(a1.y);
                va[6] = f2b(a1.z); va[7] = f2b(a1.w);
            } else {
                va = *(const u16x8*)(A + (size_t)(m0 + row) * K + k0 + cc);
            }
            *(u16x8*)(&As[row][cc]) = va;
            const int nrow = n0 + row;
            u16x8 vb = (u16x8){0, 0, 0, 0, 0, 0, 0, 0};
            if (nrow < N) vb = *(const u16x8*)(W + (size_t)nrow * K + k0 + cc);
            *(u16x8*)(&Bs[row][cc]) = vb;
        }
        __syncthreads();
        bf8_t af[4], bfr[4];
        #pragma unroll
        for (int i = 0; i < 4; ++i)
            af[i] = *(const bf8_t*)(&As[(wr << 6) + (i << 4) + r][g << 3]);
        #pragma unroll
        for (int j = 0; j < 4; ++j)
            bfr[j] = *(const bf8_t*)(&Bs[(wc << 6) + (j << 4) + r][g << 3]);
        #pragma unroll
        for (int i = 0; i < 4; ++i)
            #pragma unroll
            for (int j = 0; j < 4; ++j)
                acc[i][j] = __builtin_amdgcn_mfma_f32_16x16x32_bf16(
                    af[i], bfr[j], acc[i][j], 0, 0, 0);
        __syncthreads();
    }
    #pragma unroll
    for (int i = 0; i < 4; ++i) {
        const int mrow = m0 + (wr << 6) + (i << 4) + (g << 2);
        #pragma unroll
        for (int j = 0; j < 4; ++j) {
            const int col = n0 + (wc << 6) + (j << 4) + r;
            if (EPI == 0 && col >= N) continue;
            #pragma unroll
            for (int q = 0; q < 4; ++q) {
                const float v = acc[i][j][q];
                const int mm = mrow + q;
                if (EPI == 0) {
                    out0[(size_t)mm * N + col] = v;
                } else {
                    if (col < 256) out0[((size_t)mm << 8) + col] = v;
                    else out1[((size_t)mm << 8) + (col - 256)] = silu_f(v);
                }
            }
        }
    }
}

// ---------------------------------------------------------------------------
// Depthwise 3x3 conv (SAME) + bias + SiLU; dual write fp32 + bf16.
// ---------------------------------------------------------------------------
__global__ __launch_bounds__(256) void dwconv_silu(
    const float* __restrict__ in, const float* __restrict__ w,
    const float* __restrict__ bias, float* __restrict__ outf,
    unsigned short* __restrict__ outb) {
    const int d = threadIdx.x;
    const int bp = blockIdx.x;
    const int b = bp >> 12;
    const int sp = bp & 4095;
    const int h = sp >> 6, wc = sp & 63;
    float acc = bias[d];
    #pragma unroll
    for (int kh = 0; kh < 3; ++kh) {
        const int hh = h + kh - 1;
        if (hh < 0 || hh >= 64) continue;
        #pragma unroll
        for (int kw = 0; kw < 3; ++kw) {
            const int ww = wc + kw - 1;
            if (ww < 0 || ww >= 64) continue;
            acc = fmaf(in[(size_t)(((b << 12) + (hh << 6) + ww)) * DDIM + d],
                       w[d * 9 + kh * 3 + kw], acc);
        }
    }
    const float s = silu_f(acc);
    outf[(size_t)bp * DDIM + d] = s;
    outb[(size_t)bp * DDIM + d] = f2b(s);
}

// ---------------------------------------------------------------------------
// Scan phase A, interleaved pair: block = (b,pair,c window). Two independent
// chains in one loop for 2x ILP: chain1 = (k=pair, chunk c) forward,
// chain2 = (k=pair+2, chunk NCH-1-c) (same window, reverse traversal).
// Outputs h_end + cumulative delta for both chains. h starts at 0.
// ---------------------------------------------------------------------------
__global__ __launch_bounds__(256, 4) void scanA2i(
    const float* __restrict__ xc, const float* __restrict__ proj,
    const float* __restrict__ Alogs, const float* __restrict__ dtw,
    const float* __restrict__ dtb,
    float* __restrict__ hend, float* __restrict__ cumd) {
    const int d = threadIdx.x;
    const int blk = blockIdx.x;
    const int c = blk & (NCH - 1);
    const int g2 = blk >> 7;          // b*2 + pair
    const int pair = g2 & 1;
    const int b = g2 >> 1;
    const int kd1 = (pair << 8) + d;
    const int kd2 = kd1 + 512;
    const int bk1 = (b << 2) + pair;
    const int bk2 = bk1 + 2;

    float a01, a02;
    const bool geom = geom_check(Alogs, kd1, a01) & geom_check(Alogs, kd2, a02);

    const float4 w10 = *(const float4*)(dtw + (size_t)kd1 * 8);
    const float4 w11 = *(const float4*)(dtw + (size_t)kd1 * 8 + 4);
    const float4 w20 = *(const float4*)(dtw + (size_t)kd2 * 8);
    const float4 w21 = *(const float4*)(dtw + (size_t)kd2 * 8 + 4);
    const float bias1 = dtb[kd1], bias2 = dtb[kd2];

    float h1[16], h2[16];
    #pragma unroll
    for (int n = 0; n < 16; ++n) { h1[n] = 0.f; h2[n] = 0.f; }
    float cum1 = 0.f, cum2 = 0.f;
    const int l0 = c * LCH;
    const int boff = b << 12;

    if (geom) {
        for (int t = 0; t < LCH; ++t) {
            const int p1 = perm_idx(pair, l0 + t);
            const int p2 = perm_idx(pair, l0 + (31 - t));
            const int bpp1 = boff + p1, bpp2 = boff + p2;
            const float* pr1 = proj + (size_t)bpp1 * 160 + pair * 40;
            const float* pr2 = proj + (size_t)bpp2 * 160 + (pair + 2) * 40;
            const float u1 = xc[(size_t)bpp1 * DDIM + d];
            const float u2 = xc[(size_t)bpp2 * DDIM + d];
            const float dl1 = delta_of(pr1, w10, w11, bias1);
            const float dl2 = delta_of(pr2, w20, w21, bias2);
            const float du1 = dl1 * u1, du2 = dl2 * u2;
            cum1 += dl1; cum2 += dl2;
            float dA1[16], dA2[16];
            pow_geom(__expf(dl1 * a01), dA1);
            pow_geom(__expf(dl2 * a02), dA2);
            const float4 B1a = *(const float4*)(pr1 + 8);
            const float4 B1b = *(const float4*)(pr1 + 12);
            const float4 B1c = *(const float4*)(pr1 + 16);
            const float4 B1d = *(const float4*)(pr1 + 20);
            const float4 B2a = *(const float4*)(pr2 + 8);
            const float4 B2b = *(const float4*)(pr2 + 12);
            const float4 B2c = *(const float4*)(pr2 + 16);
            const float4 B2d = *(const float4*)(pr2 + 20);
            const float Bv1[16] = {B1a.x,B1a.y,B1a.z,B1a.w, B1b.x,B1b.y,B1b.z,B1b.w,
                                   B1c.x,B1c.y,B1c.z,B1c.w, B1d.x,B1d.y,B1d.z,B1d.w};
            const float Bv2[16] = {B2a.x,B2a.y,B2a.z,B2a.w, B2b.x,B2b.y,B2b.z,B2b.w,
                                   B2c.x,B2c.y,B2c.z,B2c.w, B2d.x,B2d.y,B2d.z,B2d.w};
            #pragma unroll
            for (int n = 0; n < 16; ++n) {
                h1[n] = fmaf(dA1[n], h1[n], du1 * Bv1[n]);
                h2[n] = fmaf(dA2[n], h2[n], du2 * Bv2[n]);
            }
        }
    } else {
        for (int t = 0; t < LCH; ++t) {
            const int p1 = perm_idx(pair, l0 + t);
            const int p2 = perm_idx(pair, l0 + (31 - t));
            const int bpp1 = boff + p1, bpp2 = boff + p2;
            const float* pr1 = proj + (size_t)bpp1 * 160 + pair * 40;
            const float* pr2 = proj + (size_t)bpp2 * 160 + (pair + 2) * 40;
            const float u1 = xc[(size_t)bpp1 * DDIM + d];
            const float u2 = xc[(size_t)bpp2 * DDIM + d];
            const float dl1 = delta_of(pr1, w10, w11, bias1);
            const float dl2 = delta_of(pr2, w20, w21, bias2);
            const float du1 = dl1 * u1, du2 = dl2 * u2;
            cum1 += dl1; cum2 += dl2;
            #pragma unroll
            for (int n = 0; n < 16; ++n) {
                const float an1 = -__expf(Alogs[(size_t)kd1 * 16 + n]);
                const float an2 = -__expf(Alogs[(size_t)kd2 * 16 + n]);
                h1[n] = fmaf(__expf(dl1 * an1), h1[n], du1 * pr1[8 + n]);
                h2[n] = fmaf(__expf(dl2 * an2), h2[n], du2 * pr2[8 + n]);
            }
        }
    }
    const size_t o1 = ((size_t)c * 4096 + (size_t)bk1 * DDIM + d) * 16;
    const size_t o2 = ((size_t)(NCH - 1 - c) * 4096 + (size_t)bk2 * DDIM + d) * 16;
    #pragma unroll
    for (int n = 0; n < 16; ++n) { hend[o1 + n] = h1[n]; hend[o2 + n] = h2[n]; }
    cumd[(size_t)(c * 16 + bk1) * DDIM + d] = cum1;
    cumd[(size_t)((NCH - 1 - c) * 16 + bk2) * DDIM + d] = cum2;
}

// ---------------------------------------------------------------------------
// Scan phase B: inter-chunk recurrence (NCH steps) over 65536 states.
// P recomputed as exp(cumDelta * a) (exact identity).
// ---------------------------------------------------------------------------
__global__ __launch_bounds__(256) void scanB(
    const float* __restrict__ hend, const float* __restrict__ cumd,
    const float* __restrict__ Alogs, float* __restrict__ H0) {
    const int tid = blockIdx.x * 256 + threadIdx.x;
    const int n = tid & 15;
    const int d = (tid >> 4) & 255;
    const int bk = tid >> 12;
    const int k = bk & 3;
    const float a = -__expf(Alogs[(size_t)(((k << 8) + d)) * 16 + n]);
    float H = 0.f;
    H0[tid] = 0.f;
    for (int c = 1; c < NCH; ++c) {
        const size_t i = (size_t)(c - 1) * 65536 + tid;
        const float P = __expf(cumd[(size_t)((c - 1) * 16 + bk) * DDIM + d] * a);
        H = fmaf(P, H, hend[i]);
        H0[(size_t)c * 65536 + tid] = H;
    }
}

// ---------------------------------------------------------------------------
// Scan phase C, interleaved pair: chain1 = (k=pair, chunk c) at window pos t,
// chain2 = (k=pair+2, chunk NCH-1-c) at window pos 31-t. Both start from
// their true initial state (H0). For t<16 buffer y in LDS (per-thread
// column, no barrier); for t>=16 emit pair-sum at both positions.
// ysp has 2 planes indexed by (b*2+pair).
// ---------------------------------------------------------------------------
__global__ __launch_bounds__(256, 4) void scanC2i(
    const float* __restrict__ xc, const float* __restrict__ proj,
    const float* __restrict__ Alogs, const float* __restrict__ dtw,
    const float* __restrict__ dtb, const float* __restrict__ Dsv,
    const float* __restrict__ H0, float* __restrict__ ysp) {
    __shared__ float buf1[16][256];
    __shared__ float buf2[16][256];
    const int d = threadIdx.x;
    const int blk = blockIdx.x;
    const int c = blk & (NCH - 1);
    const int g2 = blk >> 7;          // b*2 + pair
    const int pair = g2 & 1;
    const int b = g2 >> 1;
    const int kd1 = (pair << 8) + d;
    const int kd2 = kd1 + 512;
    const int bk1 = (b << 2) + pair;
    const int bk2 = bk1 + 2;
    const size_t planeBase = (size_t)g2 << 20;

    float a01, a02;
    const bool geom = geom_check(Alogs, kd1, a01) & geom_check(Alogs, kd2, a02);

    const float4 w10 = *(const float4*)(dtw + (size_t)kd1 * 8);
    const float4 w11 = *(const float4*)(dtw + (size_t)kd1 * 8 + 4);
    const float4 w20 = *(const float4*)(dtw + (size_t)kd2 * 8);
    const float4 w21 = *(const float4*)(dtw + (size_t)kd2 * 8 + 4);
    const float bias1 = dtb[kd1], bias2 = dtb[kd2];
    const float Dd1 = Dsv[kd1], Dd2 = Dsv[kd2];

    float h1[16], h2[16];
    const size_t ho1 = ((size_t)c * 4096 + (size_t)bk1 * DDIM + d) * 16;
    const size_t ho2 = ((size_t)(NCH - 1 - c) * 4096 + (size_t)bk2 * DDIM + d) * 16;
    #pragma unroll
    for (int n = 0; n < 16; ++n) { h1[n] = H0[ho1 + n]; h2[n] = H0[ho2 + n]; }

    const int l0 = c * LCH;
    const int boff = b << 12;

    if (geom) {
        for (int t = 0; t < LCH; ++t) {
            const int p1 = perm_idx(pair, l0 + t);
            const int p2 = perm_idx(pair, l0 + (31 - t));
            const int bpp1 = boff + p1, bpp2 = boff + p2;
            const float* pr1 = proj + (size_t)bpp1 * 160 + pair * 40;
            const float* pr2 = proj + (size_t)bpp2 * 160 + (pair + 2) * 40;
            const float u1 = xc[(size_t)bpp1 * DDIM + d];
            const float u2 = xc[(size_t)bpp2 * DDIM + d];
            const float dl1 = delta_of(pr1, w10, w11, bias1);
            const float dl2 = delta_of(pr2, w20, w21, bias2);
            const float du1 = dl1 * u1, du2 = dl2 * u2;
            float dA1[16], dA2[16];
            pow_geom(__expf(dl1 * a01), dA1);
            pow_geom(__expf(dl2 * a02), dA2);
            const float4 B1a = *(const float4*)(pr1 + 8);
            const float4 B1b = *(const float4*)(pr1 + 12);
            const float4 B1c = *(const float4*)(pr1 + 16);
            const float4 B1d = *(const float4*)(pr1 + 20);
            const float4 C1a = *(const float4*)(pr1 + 24);
            const float4 C1b = *(const float4*)(pr1 + 28);
            const float4 C1c = *(const float4*)(pr1 + 32);
            const float4 C1d = *(const float4*)(pr1 + 36);
            const float4 B2a = *(const float4*)(pr2 + 8);
            const float4 B2b = *(const float4*)(pr2 + 12);
            const float4 B2c = *(const float4*)(pr2 + 16);
            const float4 B2d = *(const float4*)(pr2 + 20);
            const float4 C2a = *(const float4*)(pr2 + 24);
            const float4 C2b = *(const float4*)(pr2 + 28);
            const float4 C2c = *(const float4*)(pr2 + 32);
            const float4 C2d = *(const float4*)(pr2 + 36);
            const float Bv1[16] = {B1a.x,B1a.y,B1a.z,B1a.w, B1b.x,B1b.y,B1b.z,B1b.w,
                                   B1c.x,B1c.y,B1c.z,B1c.w, B1d.x,B1d.y,B1d.z,B1d.w};
            const float Cv1[16] = {C1a.x,C1a.y,C1a.z,C1a.w, C1b.x,C1b.y,C1b.z,C1b.w,
                                   C1c.x,C1c.y,C1c.z,C1c.w, C1d.x,C1d.y,C1d.z,C1d.w};
            const float Bv2[16] = {B2a.x,B2a.y,B2a.z,B2a.w, B2b.x,B2b.y,B2b.z,B2b.w,
                                   B2c.x,B2c.y,B2c.z,B2c.w, B2d.x,B2d.y,B2d.z,B2d.w};
            const float Cv2[16] = {C2a.x,C2a.y,C2a.z,C2a.w, C2b.x,C2b.y,C2b.z,C2b.w,
                                   C2c.x,C2c.y,C2c.z,C2c.w, C2d.x,C2d.y,C2d.z,C2d.w};
            float y1 = 0.f, y2 = 0.f;
            #pragma unroll
            for (int n = 0; n < 16; ++n) {
                h1[n] = fmaf(dA1[n], h1[n], du1 * Bv1[n]);
                y1 = fmaf(h1[n], Cv1[n], y1);
                h2[n] = fmaf(dA2[n], h2[n], du2 * Bv2[n]);
                y2 = fmaf(h2[n], Cv2[n], y2);
            }
            y1 = fmaf(Dd1, u1, y1);
            y2 = fmaf(Dd2, u2, y2);
            if (t < 16) {
                buf1[t][d] = y1;
                buf2[15 - t][d] = y2;          // slot s holds window pos 16+s
            } else {
                ysp[planeBase + (size_t)p1 * DDIM + d] = y1 + buf2[t - 16][d];
                ysp[planeBase + (size_t)p2 * DDIM + d] = y2 + buf1[31 - t][d];
            }
        }
    } else {
        for (int t = 0; t < LCH; ++t) {
            const int p1 = perm_idx(pair, l0 + t);
            const int p2 = perm_idx(pair, l0 + (31 - t));
            const int bpp1 = boff + p1, bpp2 = boff + p2;
            const float* pr1 = proj + (size_t)bpp1 * 160 + pair * 40;
            const float* pr2 = proj + (size_t)bpp2 * 160 + (pair + 2) * 40;
            const float u1 = xc[(size_t)bpp1 * DDIM + d];
            const float u2 = xc[(size_t)bpp2 * DDIM + d];
            const float dl1 = delta_of(pr1, w10, w11, bias1);
            const float dl2 = delta_of(pr2, w20, w21, bias2);
            const float du1 = dl1 * u1, du2 = dl2 * u2;
            float y1 = 0.f, y2 = 0.f;
            #pragma unroll
            for (int n = 0; n < 16; ++n) {
                const float an1 = -__expf(Alogs[(size_t)kd1 * 16 + n]);
                const float an2 = -__expf(Alogs[(size_t)kd2 * 16 + n]);
                h1[n] = fmaf(__expf(dl1 * an1), h1[n], du1 * pr1[8 + n]);
                y1 = fmaf(h1[n], pr1[24 + n], y1);
                h2[n] = fmaf(__expf(dl2 * an2), h2[n], du2 * pr2[8 + n]);
                y2 = fmaf(h2[n], pr2[24 + n], y2);
            }
            y1 = fmaf(Dd1, u1, y1);
            y2 = fmaf(Dd2, u2, y2);
            if (t < 16) {
                buf1[t][d] = y1;
                buf2[15 - t][d] = y2;
            } else {
                ysp[planeBase + (size_t)p1 * DDIM + d] = y1 + buf2[t - 16][d];
                ysp[planeBase + (size_t)p2 * DDIM + d] = y2 + buf1[31 - t][d];
            }
        }
    }
}

// ---------------------------------------------------------------------------
// Merge 2 pair-planes + LayerNorm(D) + gate with z. Writes bf16.
// ---------------------------------------------------------------------------
__global__ __launch_bounds__(256) void merge_ln(
    const float* __restrict__ ysp, const float* __restrict__ z,
    const float* __restrict__ lnw, const float* __restrict__ lnb,
    unsigned short* __restrict__ yzb) {
    const int d = threadIdx.x;
    const int bp = blockIdx.x;
    const int b = bp >> 12;
    const int p = bp & 4095;
    const float v = ysp[(((size_t)(b << 1) << 12) + p) * DDIM + d]
                  + ysp[(((size_t)((b << 1) + 1) << 12) + p) * DDIM + d];

    __shared__ float red[4];
    float s = v;
    #pragma unroll
    for (int o = 32; o > 0; o >>= 1) s += __shfl_xor(s, o);
    const int wave = threadIdx.x >> 6;
    if ((threadIdx.x & 63) == 0) red[wave] = s;
    __syncthreads();
    const float mu = (red[0] + red[1] + red[2] + red[3]) * (1.f / 256.f);
    __syncthreads();
    const float dv = v - mu;
    float s2 = dv * dv;
    #pragma unroll
    for (int o = 32; o > 0; o >>= 1) s2 += __shfl_xor(s2, o);
    if ((threadIdx.x & 63) == 0) red[wave] = s2;
    __syncthreads();
    const float var = (red[0] + red[1] + red[2] + red[3]) * (1.f / 256.f);
    const float y = dv * rsqrtf(var + 1e-5f) * lnw[d] + lnb[d];
    yzb[(size_t)bp * DDIM + d] = f2b(y * z[(size_t)bp * DDIM + d]);
}

// ---------------------------------------------------------------------------
extern "C" void kernel_launch(void* const* d_in, const int* in_sizes, int n_in,
                              void* d_out, int out_size, void* d_ws, size_t ws_size,
                              hipStream_t stream) {
    const float* xin[2]   = {(const float*)d_in[0],  (const float*)d_in[1]};
    const float* inw[2]   = {(const float*)d_in[2],  (const float*)d_in[3]};
    const float* convw[2] = {(const float*)d_in[4],  (const float*)d_in[6]};
    const float* convb[2] = {(const float*)d_in[5],  (const float*)d_in[7]};
    const float* xpw   = (const float*)d_in[8];
    const float* dtw   = (const float*)d_in[9];
    const float* dtb   = (const float*)d_in[10];
    const float* Alogs = (const float*)d_in[11];
    const float* Dsv   = (const float*)d_in[12];
    const float* lnw   = (const float*)d_in[13];
    const float* lnb   = (const float*)d_in[14];
    const float* outw[2] = {(const float*)d_in[15], (const float*)d_in[16]};

    float* ws = (float*)d_ws;
    float* xc_raw  = ws + 0;          // 4,194,304  in_proj out (dead after conv)
    float* zbuf    = ws + 4194304;    // 4,194,304  silu(z), lives to merge_ln
    float* xc_conv = ws + 8388608;    // 4,194,304  conv out fp32 (scan input)
    float* proj    = ws + 12582912;   // 2,621,440  x_proj out
    float* hend    = ws + 15204352;   // 8,388,608  scanA -> scanB
    float* cumd    = ws + 23592960;   //   524,288  scanA -> scanB
    float* H0      = ws + 31981568;   // 8,388,608  scanB -> scanC
    float* ysp     = ws + 15204352;   // 8,388,608  2 planes (overlays dead hend)
    unsigned short* yzbf    = (unsigned short*)(ws + 0);         // xc_raw region
    unsigned short* wbf_out = (unsigned short*)(ws + 2097152);   // xc_raw region
    unsigned short* xcbf    = (unsigned short*)(ws + 24117248);  // after cumd
    unsigned short* wbf_in  = (unsigned short*)(ws + 26214400);  // free gap
    unsigned short* wbf_xp  = (unsigned short*)(ws + 26247168);  // free gap
    float* outp = (float*)d_out;

    for (int s = 0; s < 2; ++s) {
        cvt_bf16<<<32, 256, 0, stream>>>(inw[s], wbf_in, 8192);   // 512x128
        cvt_bf16<<<20, 256, 0, stream>>>(xpw, wbf_xp, 5120);      // 160x256
        gemm_bf<1, true><<<dim3(4, 128), 256, 0, stream>>>(
            nullptr, xin[s], wbf_in, xc_raw, zbuf, 512, 128);
        dwconv_silu<<<16384, 256, 0, stream>>>(xc_raw, convw[s], convb[s],
                                               xc_conv, xcbf);
        cvt_bf16<<<16, 256, 0, stream>>>(outw[s], wbf_out, 4096); // 128x256
        gemm_bf<0, false><<<dim3(2, 128), 256, 0, stream>>>(
            xcbf, nullptr, wbf_xp, proj, nullptr, 160, 256);
        scanA2i<<<8 * NCH, 256, 0, stream>>>(xc_conv, proj, Alogs, dtw, dtb,
                                             hend, cumd);
        scanB<<<256, 256, 0, stream>>>(hend, cumd, Alogs, H0);
        scanC2i<<<8 * NCH, 256, 0, stream>>>(xc_conv, proj, Alogs, dtw, dtb,
                                             Dsv, H0, ysp);
        merge_ln<<<16384, 256, 0, stream>>>(ysp, zbuf, lnw, lnb, yzbf);
        gemm_bf<0, false><<<dim3(1, 128), 256, 0, stream>>>(
            yzbf, nullptr, wbf_out, outp + (size_t)s * 2097152, nullptr,
            128, 256);
    }
}

// Round 6
// 493.183 us; speedup vs baseline: 1.0665x; 1.0665x over previous
//
#include <hip/hip_runtime.h>
#include <hip/hip_bf16.h>
#include <math.h>

// Problem constants (B=4, H=W=64, C=128, DI=256, N=16, R=8, K=4)
#define DDIM 256
#define NCH  128
#define LCH  32

typedef __attribute__((ext_vector_type(8))) short bf8_t;
typedef __attribute__((ext_vector_type(2))) float f32x2;
typedef __attribute__((ext_vector_type(4))) float f32x4;
typedef __attribute__((ext_vector_type(8))) unsigned short u16x8;

__device__ __forceinline__ float silu_f(float x) {
    return x / (1.f + __expf(-x));
}
__device__ __forceinline__ float softplus_f(float x) {
    return fmaxf(x, 0.f) + __logf(1.f + __expf(-fabsf(x)));
}
__device__ __forceinline__ unsigned short f2b(float x) {
    union { __hip_bfloat16 h; unsigned short u; } v;
    v.h = __float2bfloat16(x);
    return v.u;
}
__device__ __forceinline__ int perm_idx(int k, int l) {
    switch (k & 3) {
        case 0: return l;
        case 1: return ((l & 63) << 6) | (l >> 6);
        case 2: return 4095 - l;
        default: { int lr = 4095 - l; return ((lr & 63) << 6) | (lr >> 6); }
    }
}
// packed fp32 (VOP3P): 2 FMA/mul per instruction
__device__ __forceinline__ f32x2 pk_fma(f32x2 a, f32x2 b, f32x2 c) {
    f32x2 d;
    asm("v_pk_fma_f32 %0, %1, %2, %3" : "=v"(d) : "v"(a), "v"(b), "v"(c));
    return d;
}
__device__ __forceinline__ f32x2 pk_mul(f32x2 a, f32x2 b) {
    f32x2 d;
    asm("v_pk_mul_f32 %0, %1, %2" : "=v"(d) : "v"(a), "v"(b));
    return d;
}
// dA pair j = (e1^(2j+1), e1^(2j+2)); 1 scalar mul + 7 packed muls
__device__ __forceinline__ void pow_geom_pk(float e1, f32x2 dA[8]) {
    const float e2 = e1 * e1;
    const f32x2 s = (f32x2){e2, e2};
    dA[0] = (f32x2){e1, e2};
    dA[1] = pk_mul(dA[0], s);
    dA[2] = pk_mul(dA[1], s);
    dA[3] = pk_mul(dA[2], s);
    dA[4] = pk_mul(dA[3], s);
    dA[5] = pk_mul(dA[4], s);
    dA[6] = pk_mul(dA[5], s);
    dA[7] = pk_mul(dA[6], s);
}
// delta = softplus(bias + dot8(proj_dt, w8)) with float4 loads
__device__ __forceinline__ float delta_of(const float* pr0, const float4 w0,
                                          const float4 w1, float bias) {
    const float4 p0 = *(const float4*)pr0;
    const float4 p1 = *(const float4*)(pr0 + 4);
    float x = bias;
    x = fmaf(p0.x, w0.x, x); x = fmaf(p0.y, w0.y, x);
    x = fmaf(p0.z, w0.z, x); x = fmaf(p0.w, w0.w, x);
    x = fmaf(p1.x, w1.x, x); x = fmaf(p1.y, w1.y, x);
    x = fmaf(p1.z, w1.z, x); x = fmaf(p1.w, w1.w, x);
    return softplus_f(x);
}
__device__ __forceinline__ bool geom_check(const float* Alogs, int kd, float& a0) {
    a0 = -__expf(Alogs[(size_t)kd * 16]);
    bool g = true;
    #pragma unroll
    for (int n = 1; n < 16; ++n) {
        const float an = -__expf(Alogs[(size_t)kd * 16 + n]);
        const float rr = a0 * (float)(n + 1);
        g = g && (fabsf(an - rr) <= 1e-4f * fabsf(rr));
    }
    return g;
}

// ---------------------------------------------------------------------------
// fp32 -> bf16 conversion (weights only)
// ---------------------------------------------------------------------------
__global__ __launch_bounds__(256) void cvt_bf16(
    const float* __restrict__ in, unsigned short* __restrict__ out, int n8) {
    const int i = blockIdx.x * 256 + threadIdx.x;
    if (i >= n8) return;
    const float4 a = ((const float4*)in)[i * 2];
    const float4 b = ((const float4*)in)[i * 2 + 1];
    u16x8 r;
    r[0] = f2b(a.x); r[1] = f2b(a.y); r[2] = f2b(a.z); r[3] = f2b(a.w);
    r[4] = f2b(b.x); r[5] = f2b(b.y); r[6] = f2b(b.z); r[7] = f2b(b.w);
    *(u16x8*)(out + (size_t)i * 8) = r;
}

// ---------------------------------------------------------------------------
// bf16 MFMA GEMM: out[m,n] = sum_k A[m,k] * W[n,k]  (W: NxK bf16)
// ---------------------------------------------------------------------------
template <int EPI, bool AF32>
__global__ __launch_bounds__(256) void gemm_bf(
    const unsigned short* __restrict__ A, const float* __restrict__ Af,
    const unsigned short* __restrict__ W,
    float* __restrict__ out0, float* __restrict__ out1, int N, int K) {
    __shared__ unsigned short As[128][40];
    __shared__ unsigned short Bs[128][40];
    const int tid = threadIdx.x;
    const int lane = tid & 63;
    const int wid = tid >> 6;
    const int wr = wid >> 1, wc = wid & 1;
    const int m0 = blockIdx.y << 7, n0 = blockIdx.x << 7;
    const int r = lane & 15, g = lane >> 4;
    f32x4 acc[4][4];
    #pragma unroll
    for (int i = 0; i < 4; ++i)
        #pragma unroll
        for (int j = 0; j < 4; ++j) acc[i][j] = (f32x4){0.f, 0.f, 0.f, 0.f};
    const int row0 = tid >> 2;       // 0..63
    const int cc = (tid & 3) << 3;   // 0,8,16,24

    for (int k0 = 0; k0 < K; k0 += 32) {
        #pragma unroll
        for (int h = 0; h < 2; ++h) {
            const int row = row0 + (h << 6);
            u16x8 va;
            if (AF32) {
                const float* ap = Af + (size_t)(m0 + row) * K + k0 + cc;
                const float4 a0 = *(const float4*)ap;
                const float4 a1 = *(const float4*)(ap + 4);
                va[0] = f2b(a0.x); va[1] = f2b(a0.y);
                va[2] = f2b(a0.z); va[3] = f2b(a0.w);
                va[4] = f2b(a1.x); va[5] = f2b(a1.y);
                va[6] = f2b(a1.z); va[7] = f2b(a1.w);
            } else {
                va = *(const u16x8*)(A + (size_t)(m0 + row) * K + k0 + cc);
            }
            *(u16x8*)(&As[row][cc]) = va;
            const int nrow = n0 + row;
            u16x8 vb = (u16x8){0, 0, 0, 0, 0, 0, 0, 0};
            if (nrow < N) vb = *(const u16x8*)(W + (size_t)nrow * K + k0 + cc);
            *(u16x8*)(&Bs[row][cc]) = vb;
        }
        __syncthreads();
        bf8_t af[4], bfr[4];
        #pragma unroll
        for (int i = 0; i < 4; ++i)
            af[i] = *(const bf8_t*)(&As[(wr << 6) + (i << 4) + r][g << 3]);
        #pragma unroll
        for (int j = 0; j < 4; ++j)
            bfr[j] = *(const bf8_t*)(&Bs[(wc << 6) + (j << 4) + r][g << 3]);
        #pragma unroll
        for (int i = 0; i < 4; ++i)
            #pragma unroll
            for (int j = 0; j < 4; ++j)
                acc[i][j] = __builtin_amdgcn_mfma_f32_16x16x32_bf16(
                    af[i], bfr[j], acc[i][j], 0, 0, 0);
        __syncthreads();
    }
    #pragma unroll
    for (int i = 0; i < 4; ++i) {
        const int mrow = m0 + (wr << 6) + (i << 4) + (g << 2);
        #pragma unroll
        for (int j = 0; j < 4; ++j) {
            const int col = n0 + (wc << 6) + (j << 4) + r;
            if (EPI == 0 && col >= N) continue;
            #pragma unroll
            for (int q = 0; q < 4; ++q) {
                const float v = acc[i][j][q];
                const int mm = mrow + q;
                if (EPI == 0) {
                    out0[(size_t)mm * N + col] = v;
                } else {
                    if (col < 256) out0[((size_t)mm << 8) + col] = v;
                    else out1[((size_t)mm << 8) + (col - 256)] = silu_f(v);
                }
            }
        }
    }
}

// ---------------------------------------------------------------------------
// Depthwise 3x3 conv (SAME) + bias + SiLU; dual write fp32 + bf16.
// ---------------------------------------------------------------------------
__global__ __launch_bounds__(256) void dwconv_silu(
    const float* __restrict__ in, const float* __restrict__ w,
    const float* __restrict__ bias, float* __restrict__ outf,
    unsigned short* __restrict__ outb) {
    const int d = threadIdx.x;
    const int bp = blockIdx.x;
    const int b = bp >> 12;
    const int sp = bp & 4095;
    const int h = sp >> 6, wc = sp & 63;
    float acc = bias[d];
    #pragma unroll
    for (int kh = 0; kh < 3; ++kh) {
        const int hh = h + kh - 1;
        if (hh < 0 || hh >= 64) continue;
        #pragma unroll
        for (int kw = 0; kw < 3; ++kw) {
            const int ww = wc + kw - 1;
            if (ww < 0 || ww >= 64) continue;
            acc = fmaf(in[(size_t)(((b << 12) + (hh << 6) + ww)) * DDIM + d],
                       w[d * 9 + kh * 3 + kw], acc);
        }
    }
    const float s = silu_f(acc);
    outf[(size_t)bp * DDIM + d] = s;
    outb[(size_t)bp * DDIM + d] = f2b(s);
}

// ---------------------------------------------------------------------------
// Scan phase A: per-chunk local scan from h=0, packed fp32 math.
// blockIdx = bk*NCH + chunk; threads = d. Outputs h_end + cumulative delta.
// ---------------------------------------------------------------------------
__global__ __launch_bounds__(256) void scanA(
    const float* __restrict__ xc, const float* __restrict__ proj,
    const float* __restrict__ Alogs, const float* __restrict__ dtw,
    const float* __restrict__ dtb,
    float* __restrict__ hend, float* __restrict__ cumd) {
    const int d = threadIdx.x;
    const int blk = blockIdx.x;
    const int c = blk & (NCH - 1);
    const int bk = blk >> 7;
    const int k = bk & 3;
    const int b = bk >> 2;
    const int kd = (k << 8) + d;

    float a0;
    const bool geom = geom_check(Alogs, kd, a0);
    const float4 w0 = *(const float4*)(dtw + (size_t)kd * 8);
    const float4 w1 = *(const float4*)(dtw + (size_t)kd * 8 + 4);
    const float bias = dtb[kd];

    float cum = 0.f;
    const int l0 = c * LCH;
    const int boff = b << 12;
    const size_t o = ((size_t)c * 4096 + (size_t)bk * DDIM + d) * 16;

    if (geom) {
        f32x2 h[8];
        #pragma unroll
        for (int j = 0; j < 8; ++j) h[j] = (f32x2){0.f, 0.f};
        for (int t = 0; t < LCH; ++t) {
            const int p = perm_idx(k, l0 + t);
            const int bpp = boff + p;
            const float* pr0 = proj + (size_t)bpp * 160 + k * 40;
            const float delta = delta_of(pr0, w0, w1, bias);
            const float u = xc[(size_t)bpp * DDIM + d];
            const float du = delta * u;
            cum += delta;
            f32x2 dA[8];
            pow_geom_pk(__expf(delta * a0), dA);
            const float4 Ba = *(const float4*)(pr0 + 8);
            const float4 Bb = *(const float4*)(pr0 + 12);
            const float4 Bc = *(const float4*)(pr0 + 16);
            const float4 Bd = *(const float4*)(pr0 + 20);
            const f32x2 Bv[8] = {
                {Ba.x, Ba.y}, {Ba.z, Ba.w}, {Bb.x, Bb.y}, {Bb.z, Bb.w},
                {Bc.x, Bc.y}, {Bc.z, Bc.w}, {Bd.x, Bd.y}, {Bd.z, Bd.w}};
            const f32x2 du2 = (f32x2){du, du};
            #pragma unroll
            for (int j = 0; j < 8; ++j)
                h[j] = pk_fma(dA[j], h[j], pk_mul(du2, Bv[j]));
        }
        #pragma unroll
        for (int j = 0; j < 8; ++j) {
            hend[o + 2 * j] = h[j][0];
            hend[o + 2 * j + 1] = h[j][1];
        }
    } else {
        float h[16];
        #pragma unroll
        for (int n = 0; n < 16; ++n) h[n] = 0.f;
        for (int t = 0; t < LCH; ++t) {
            const int p = perm_idx(k, l0 + t);
            const int bpp = boff + p;
            const float* pr0 = proj + (size_t)bpp * 160 + k * 40;
            const float delta = delta_of(pr0, w0, w1, bias);
            const float u = xc[(size_t)bpp * DDIM + d];
            const float du = delta * u;
            cum += delta;
            #pragma unroll
            for (int n = 0; n < 16; ++n) {
                const float an = -__expf(Alogs[(size_t)kd * 16 + n]);
                h[n] = fmaf(__expf(delta * an), h[n], du * pr0[8 + n]);
            }
        }
        #pragma unroll
        for (int n = 0; n < 16; ++n) hend[o + n] = h[n];
    }
    cumd[(size_t)(c * 16 + bk) * DDIM + d] = cum;
}

// ---------------------------------------------------------------------------
// Scan phase B: inter-chunk recurrence (NCH steps) over 65536 states.
// P recomputed as exp(cumDelta * a) (exact identity).
// ---------------------------------------------------------------------------
__global__ __launch_bounds__(256) void scanB(
    const float* __restrict__ hend, const float* __restrict__ cumd,
    const float* __restrict__ Alogs, float* __restrict__ H0) {
    const int tid = blockIdx.x * 256 + threadIdx.x;
    const int n = tid & 15;
    const int d = (tid >> 4) & 255;
    const int bk = tid >> 12;
    const int k = bk & 3;
    const float a = -__expf(Alogs[(size_t)(((k << 8) + d)) * 16 + n]);
    float H = 0.f;
    H0[tid] = 0.f;
    for (int c = 1; c < NCH; ++c) {
        const size_t i = (size_t)(c - 1) * 65536 + tid;
        const float P = __expf(cumd[(size_t)((c - 1) * 16 + bk) * DDIM + d] * a);
        H = fmaf(P, H, hend[i]);
        H0[(size_t)c * 65536 + tid] = H;
    }
}

// ---------------------------------------------------------------------------
// Scan phase C chunk worker (packed fp32): run one chunk of direction k from
// its true initial state. EMIT=0: y -> ybuf[t][d]. EMIT=1: emit
// ybuf[31-t][d] + y to ysp plane at spatial position.
// ---------------------------------------------------------------------------
template <int EMIT>
__device__ __forceinline__ void scanC_chunk(
    const int k, const int chunk, const int b, const int d,
    const float* __restrict__ xc, const float* __restrict__ proj,
    const float* __restrict__ Alogs, const float* __restrict__ dtw,
    const float* __restrict__ dtb, const float* __restrict__ Dsv,
    const float* __restrict__ H0, float* __restrict__ ysp,
    float (*ybuf)[256], const size_t planeBase) {
    const int kd = (k << 8) + d;
    const int bk = (b << 2) + k;

    float a0;
    const bool geom = geom_check(Alogs, kd, a0);
    const float4 w0 = *(const float4*)(dtw + (size_t)kd * 8);
    const float4 w1 = *(const float4*)(dtw + (size_t)kd * 8 + 4);
    const float bias = dtb[kd];
    const float Dd = Dsv[kd];

    const size_t ho = ((size_t)chunk * 4096 + (size_t)bk * DDIM + d) * 16;
    const int l0 = chunk * LCH;
    const int boff = b << 12;

    if (geom) {
        f32x2 h[8];
        const f32x2* hp = (const f32x2*)(H0 + ho);
        #pragma unroll
        for (int j = 0; j < 8; ++j) h[j] = hp[j];
        for (int t = 0; t < LCH; ++t) {
            const int p = perm_idx(k, l0 + t);
            const int bpp = boff + p;
            const float* pr0 = proj + (size_t)bpp * 160 + k * 40;
            const float delta = delta_of(pr0, w0, w1, bias);
            const float u = xc[(size_t)bpp * DDIM + d];
            const float du = delta * u;
            f32x2 dA[8];
            pow_geom_pk(__expf(delta * a0), dA);
            const float4 Ba = *(const float4*)(pr0 + 8);
            const float4 Bb = *(const float4*)(pr0 + 12);
            const float4 Bc = *(const float4*)(pr0 + 16);
            const float4 Bd = *(const float4*)(pr0 + 20);
            const float4 Ca = *(const float4*)(pr0 + 24);
            const float4 Cb = *(const float4*)(pr0 + 28);
            const float4 Cc = *(const float4*)(pr0 + 32);
            const float4 Cd = *(const float4*)(pr0 + 36);
            const f32x2 Bv[8] = {
                {Ba.x, Ba.y}, {Ba.z, Ba.w}, {Bb.x, Bb.y}, {Bb.z, Bb.w},
                {Bc.x, Bc.y}, {Bc.z, Bc.w}, {Bd.x, Bd.y}, {Bd.z, Bd.w}};
            const f32x2 Cv[8] = {
                {Ca.x, Ca.y}, {Ca.z, Ca.w}, {Cb.x, Cb.y}, {Cb.z, Cb.w},
                {Cc.x, Cc.y}, {Cc.z, Cc.w}, {Cd.x, Cd.y}, {Cd.z, Cd.w}};
            const f32x2 du2 = (f32x2){du, du};
            f32x2 y2 = (f32x2){0.f, 0.f};
            #pragma unroll
            for (int j = 0; j < 8; ++j) {
                h[j] = pk_fma(dA[j], h[j], pk_mul(du2, Bv[j]));
                y2 = pk_fma(h[j], Cv[j], y2);
            }
            float y = y2[0] + y2[1];
            y = fmaf(Dd, u, y);
            if (EMIT == 0) ybuf[t][d] = y;
            else ysp[planeBase + (size_t)p * DDIM + d] = y + ybuf[31 - t][d];
        }
    } else {
        float h[16];
        #pragma unroll
        for (int n = 0; n < 16; ++n) h[n] = H0[ho + n];
        for (int t = 0; t < LCH; ++t) {
            const int p = perm_idx(k, l0 + t);
            const int bpp = boff + p;
            const float* pr0 = proj + (size_t)bpp * 160 + k * 40;
            const float delta = delta_of(pr0, w0, w1, bias);
            const float u = xc[(size_t)bpp * DDIM + d];
            const float du = delta * u;
            float y = 0.f;
            #pragma unroll
            for (int n = 0; n < 16; ++n) {
                const float an = -__expf(Alogs[(size_t)kd * 16 + n]);
                h[n] = fmaf(__expf(delta * an), h[n], du * pr0[8 + n]);
                y = fmaf(h[n], pr0[24 + n], y);
            }
            y = fmaf(Dd, u, y);
            if (EMIT == 0) ybuf[t][d] = y;
            else ysp[planeBase + (size_t)p * DDIM + d] = y + ybuf[31 - t][d];
        }
    }
}

// ---------------------------------------------------------------------------
// Scan phase C, pair-fused: block handles (k=pair, chunk c) then
// (k=pair+2, chunk NCH-1-c); same 32-position window so the pair-sum is
// emitted directly. ysp has 2 planes. blockIdx = (b*2+pair)*NCH + c
// ---------------------------------------------------------------------------
__global__ __launch_bounds__(256) void scanC2(
    const float* __restrict__ xc, const float* __restrict__ proj,
    const float* __restrict__ Alogs, const float* __restrict__ dtw,
    const float* __restrict__ dtb, const float* __restrict__ Dsv,
    const float* __restrict__ H0, float* __restrict__ ysp) {
    __shared__ float ybuf[LCH][256];
    const int d = threadIdx.x;
    const int blk = blockIdx.x;
    const int c = blk & (NCH - 1);
    const int bp2 = blk >> 7;
    const int pair = bp2 & 1;
    const int b = bp2 >> 1;
    const size_t planeBase = (size_t)bp2 << 20;  // bp2 * 4096 * 256
    scanC_chunk<0>(pair, c, b, d, xc, proj, Alogs, dtw, dtb, Dsv, H0,
                   ysp, ybuf, planeBase);
    scanC_chunk<1>(pair + 2, NCH - 1 - c, b, d, xc, proj, Alogs, dtw, dtb,
                   Dsv, H0, ysp, ybuf, planeBase);
}

// ---------------------------------------------------------------------------
// Merge 2 pair-planes + LayerNorm(D) + gate with z. Writes bf16.
// ---------------------------------------------------------------------------
__global__ __launch_bounds__(256) void merge_ln(
    const float* __restrict__ ysp, const float* __restrict__ z,
    const float* __restrict__ lnw, const float* __restrict__ lnb,
    unsigned short* __restrict__ yzb) {
    const int d = threadIdx.x;
    const int bp = blockIdx.x;
    const int b = bp >> 12;
    const int p = bp & 4095;
    const float v = ysp[(((size_t)(b << 1) << 12) + p) * DDIM + d]
                  + ysp[(((size_t)((b << 1) + 1) << 12) + p) * DDIM + d];

    __shared__ float red[4];
    float s = v;
    #pragma unroll
    for (int o = 32; o > 0; o >>= 1) s += __shfl_xor(s, o);
    const int wave = threadIdx.x >> 6;
    if ((threadIdx.x & 63) == 0) red[wave] = s;
    __syncthreads();
    const float mu = (red[0] + red[1] + red[2] + red[3]) * (1.f / 256.f);
    __syncthreads();
    const float dv = v - mu;
    float s2 = dv * dv;
    #pragma unroll
    for (int o = 32; o > 0; o >>= 1) s2 += __shfl_xor(s2, o);
    if ((threadIdx.x & 63) == 0) red[wave] = s2;
    __syncthreads();
    const float var = (red[0] + red[1] + red[2] + red[3]) * (1.f / 256.f);
    const float y = dv * rsqrtf(var + 1e-5f) * lnw[d] + lnb[d];
    yzb[(size_t)bp * DDIM + d] = f2b(y * z[(size_t)bp * DDIM + d]);
}

// ---------------------------------------------------------------------------
extern "C" void kernel_launch(void* const* d_in, const int* in_sizes, int n_in,
                              void* d_out, int out_size, void* d_ws, size_t ws_size,
                              hipStream_t stream) {
    const float* xin[2]   = {(const float*)d_in[0],  (const float*)d_in[1]};
    const float* inw[2]   = {(const float*)d_in[2],  (const float*)d_in[3]};
    const float* convw[2] = {(const float*)d_in[4],  (const float*)d_in[6]};
    const float* convb[2] = {(const float*)d_in[5],  (const float*)d_in[7]};
    const float* xpw   = (const float*)d_in[8];
    const float* dtw   = (const float*)d_in[9];
    const float* dtb   = (const float*)d_in[10];
    const float* Alogs = (const float*)d_in[11];
    const float* Dsv   = (const float*)d_in[12];
    const float* lnw   = (const float*)d_in[13];
    const float* lnb   = (const float*)d_in[14];
    const float* outw[2] = {(const float*)d_in[15], (const float*)d_in[16]};

    float* ws = (float*)d_ws;
    float* xc_raw  = ws + 0;          // 4,194,304  in_proj out (dead after conv)
    float* zbuf    = ws + 4194304;    // 4,194,304  silu(z), lives to merge_ln
    float* xc_conv = ws + 8388608;    // 4,194,304  conv out fp32 (scan input)
    float* proj    = ws + 12582912;   // 2,621,440  x_proj out
    float* hend    = ws + 15204352;   // 8,388,608  scanA -> scanB
    float* cumd    = ws + 23592960;   //   524,288  scanA -> scanB
    float* H0      = ws + 31981568;   // 8,388,608  scanB -> scanC
    float* ysp     = ws + 15204352;   // 8,388,608  2 planes (overlays dead hend)
    unsigned short* yzbf    = (unsigned short*)(ws + 0);         // xc_raw region
    unsigned short* wbf_out = (unsigned short*)(ws + 2097152);   // xc_raw region
    unsigned short* xcbf    = (unsigned short*)(ws + 24117248);  // after cumd
    unsigned short* wbf_in  = (unsigned short*)(ws + 26214400);  // free gap
    unsigned short* wbf_xp  = (unsigned short*)(ws + 26247168);  // free gap
    float* outp = (float*)d_out;

    // x_proj weight is stream-invariant: convert once
    cvt_bf16<<<20, 256, 0, stream>>>(xpw, wbf_xp, 5120);          // 160x256

    for (int s = 0; s < 2; ++s) {
        cvt_bf16<<<32, 256, 0, stream>>>(inw[s], wbf_in, 8192);   // 512x128
        gemm_bf<1, true><<<dim3(4, 128), 256, 0, stream>>>(
            nullptr, xin[s], wbf_in, xc_raw, zbuf, 512, 128);
        dwconv_silu<<<16384, 256, 0, stream>>>(xc_raw, convw[s], convb[s],
                                               xc_conv, xcbf);
        cvt_bf16<<<16, 256, 0, stream>>>(outw[s], wbf_out, 4096); // 128x256
        gemm_bf<0, false><<<dim3(2, 128), 256, 0, stream>>>(
            xcbf, nullptr, wbf_xp, proj, nullptr, 160, 256);
        scanA<<<16 * NCH, 256, 0, stream>>>(xc_conv, proj, Alogs, dtw, dtb,
                                            hend, cumd);
        scanB<<<256, 256, 0, stream>>>(hend, cumd, Alogs, H0);
        scanC2<<<8 * NCH, 256, 0, stream>>>(xc_conv, proj, Alogs, dtw, dtb,
                                            Dsv, H0, ysp);
        merge_ln<<<16384, 256, 0, stream>>>(ysp, zbuf, lnw, lnb, yzbf);
        gemm_bf<0, false><<<dim3(1, 128), 256, 0, stream>>>(
            yzbf, nullptr, wbf_out, outp + (size_t)s * 2097152, nullptr,
            128, 256);
    }
}

// Round 7
// 327.294 us; speedup vs baseline: 1.6071x; 1.5069x over previous
//
#include <hip/hip_runtime.h>
#include <hip/hip_bf16.h>
#include <math.h>

// Problem constants (B=4, H=W=64, C=128, DI=256, N=16, R=8, K=4)
// BATCHED over the 2 streams: 8 images, 32768 rows, 32 bk channel-groups.
#define DDIM 256
#define NCH  128
#define LCH  32

typedef __attribute__((ext_vector_type(8))) short bf8_t;
typedef __attribute__((ext_vector_type(4))) float f32x4;
typedef __attribute__((ext_vector_type(8))) unsigned short u16x8;
typedef _Float16 f16;

__device__ __forceinline__ float silu_f(float x) {
    return x / (1.f + __expf(-x));
}
__device__ __forceinline__ float softplus_f(float x) {
    return fmaxf(x, 0.f) + __logf(1.f + __expf(-fabsf(x)));
}
__device__ __forceinline__ unsigned short f2b(float x) {
    union { __hip_bfloat16 h; unsigned short u; } v;
    v.h = __float2bfloat16(x);
    return v.u;
}
__device__ __forceinline__ float b2f(unsigned short u) {
    union { float f; unsigned int i; } v;
    v.i = ((unsigned int)u) << 16;
    return v.f;
}
__device__ __forceinline__ int perm_idx(int k, int l) {
    switch (k & 3) {
        case 0: return l;
        case 1: return ((l & 63) << 6) | (l >> 6);
        case 2: return 4095 - l;
        default: { int lr = 4095 - l; return ((lr & 63) << 6) | (lr >> 6); }
    }
}
// dA[n] = e1^(n+1), log-depth mul tree
__device__ __forceinline__ void pow_geom(float e1, float dA[16]) {
    const float e2 = e1 * e1, e4 = e2 * e2, e8 = e4 * e4;
    dA[0] = e1;       dA[1] = e2;       dA[2] = e2 * e1;  dA[3] = e4;
    dA[4] = e4 * e1;  dA[5] = e4 * e2;  dA[6] = e4 * dA[2]; dA[7] = e8;
    dA[8] = e8 * e1;  dA[9] = e8 * e2;  dA[10] = e8 * dA[2]; dA[11] = e8 * e4;
    dA[12] = e8 * dA[4]; dA[13] = e8 * dA[5]; dA[14] = e8 * dA[6]; dA[15] = e8 * e8;
}
__device__ __forceinline__ float delta_of(const float* pr0, const float4 w0,
                                          const float4 w1, float bias) {
    const float4 p0 = *(const float4*)pr0;
    const float4 p1 = *(const float4*)(pr0 + 4);
    float x = bias;
    x = fmaf(p0.x, w0.x, x); x = fmaf(p0.y, w0.y, x);
    x = fmaf(p0.z, w0.z, x); x = fmaf(p0.w, w0.w, x);
    x = fmaf(p1.x, w1.x, x); x = fmaf(p1.y, w1.y, x);
    x = fmaf(p1.z, w1.z, x); x = fmaf(p1.w, w1.w, x);
    return softplus_f(x);
}
__device__ __forceinline__ bool geom_check(const float* Alogs, int kd, float& a0) {
    a0 = -__expf(Alogs[(size_t)kd * 16]);
    bool g = true;
    #pragma unroll
    for (int n = 1; n < 16; ++n) {
        const float an = -__expf(Alogs[(size_t)kd * 16 + n]);
        const float rr = a0 * (float)(n + 1);
        g = g && (fabsf(an - rr) <= 1e-4f * fabsf(rr));
    }
    return g;
}

// ---------------------------------------------------------------------------
// Convert all 5 weight tensors fp32->bf16 in one launch.
// segments (groups of 8): in0 8192 | in1 8192 | xp 5120 | out0 4096 | out1 4096
// ---------------------------------------------------------------------------
__global__ __launch_bounds__(256) void cvt_all(
    const float* __restrict__ s0, const float* __restrict__ s1,
    const float* __restrict__ s2, const float* __restrict__ s3,
    const float* __restrict__ s4, unsigned short* __restrict__ w) {
    const int i = blockIdx.x * 256 + threadIdx.x;
    const float* src; size_t so, oo;
    if (i < 8192)       { src = s0; so = i;         oo = 0; }
    else if (i < 16384) { src = s1; so = i - 8192;  oo = 65536; }
    else if (i < 21504) { src = s2; so = i - 16384; oo = 131072; }
    else if (i < 25600) { src = s3; so = i - 21504; oo = 172032; }
    else if (i < 29696) { src = s4; so = i - 25600; oo = 204800; }
    else return;
    const float4 a = ((const float4*)src)[so * 2];
    const float4 b = ((const float4*)src)[so * 2 + 1];
    u16x8 r;
    r[0] = f2b(a.x); r[1] = f2b(a.y); r[2] = f2b(a.z); r[3] = f2b(a.w);
    r[4] = f2b(b.x); r[5] = f2b(b.y); r[6] = f2b(b.z); r[7] = f2b(b.w);
    *(u16x8*)(w + oo + so * 8) = r;
}

// ---------------------------------------------------------------------------
// bf16 MFMA GEMM (batched 2-stream): out[m,n] = sum_k A[m,k] * W[n,k].
// W (and fp32-A source) selected per 128-row tile by m0>=msplit.
// EPI=0: plain f32 store. EPI=1: in_proj split (xc f32 | silu->bf16 z).
// EPI=2: out_proj, per-stream output offset.
// ---------------------------------------------------------------------------
template <int EPI, bool AF32>
__global__ __launch_bounds__(256) void gemm_bf(
    const unsigned short* __restrict__ A,
    const float* __restrict__ Af0, const float* __restrict__ Af1,
    const unsigned short* __restrict__ W0, const unsigned short* __restrict__ W1,
    float* __restrict__ out0, unsigned short* __restrict__ out1b,
    int N, int K, int msplit) {
    __shared__ unsigned short As[128][40];
    __shared__ unsigned short Bs[128][40];
    const int tid = threadIdx.x;
    const int lane = tid & 63;
    const int wid = tid >> 6;
    const int wr = wid >> 1, wc = wid & 1;
    const int m0 = blockIdx.y << 7, n0 = blockIdx.x << 7;
    const int sidx = (m0 >= msplit) ? 1 : 0;
    const int rbase = sidx ? msplit : 0;
    const float* Af = sidx ? Af1 : Af0;
    const unsigned short* W = sidx ? W1 : W0;
    const int r = lane & 15, g = lane >> 4;
    f32x4 acc[4][4];
    #pragma unroll
    for (int i = 0; i < 4; ++i)
        #pragma unroll
        for (int j = 0; j < 4; ++j) acc[i][j] = (f32x4){0.f, 0.f, 0.f, 0.f};
    const int row0 = tid >> 2;       // 0..63
    const int cc = (tid & 3) << 3;   // 0,8,16,24

    for (int k0 = 0; k0 < K; k0 += 32) {
        #pragma unroll
        for (int h = 0; h < 2; ++h) {
            const int row = row0 + (h << 6);
            u16x8 va;
            if (AF32) {
                const float* ap = Af + (size_t)(m0 + row - rbase) * K + k0 + cc;
                const float4 a0 = *(const float4*)ap;
                const float4 a1 = *(const float4*)(ap + 4);
                va[0] = f2b(a0.x); va[1] = f2b(a0.y);
                va[2] = f2b(a0.z); va[3] = f2b(a0.w);
                va[4] = f2b(a1.x); va[5] = f2b(a1.y);
                va[6] = f2b(a1.z); va[7] = f2b(a1.w);
            } else {
                va = *(const u16x8*)(A + (size_t)(m0 + row) * K + k0 + cc);
            }
            *(u16x8*)(&As[row][cc]) = va;
            const int nrow = n0 + row;
            u16x8 vb = (u16x8){0, 0, 0, 0, 0, 0, 0, 0};
            if (nrow < N) vb = *(const u16x8*)(W + (size_t)nrow * K + k0 + cc);
            *(u16x8*)(&Bs[row][cc]) = vb;
        }
        __syncthreads();
        bf8_t af[4], bfr[4];
        #pragma unroll
        for (int i = 0; i < 4; ++i)
            af[i] = *(const bf8_t*)(&As[(wr << 6) + (i << 4) + r][g << 3]);
        #pragma unroll
        for (int j = 0; j < 4; ++j)
            bfr[j] = *(const bf8_t*)(&Bs[(wc << 6) + (j << 4) + r][g << 3]);
        #pragma unroll
        for (int i = 0; i < 4; ++i)
            #pragma unroll
            for (int j = 0; j < 4; ++j)
                acc[i][j] = __builtin_amdgcn_mfma_f32_16x16x32_bf16(
                    af[i], bfr[j], acc[i][j], 0, 0, 0);
        __syncthreads();
    }
    // epilogue: C/D layout col=lane&15, row=(lane>>4)*4+reg
    #pragma unroll
    for (int i = 0; i < 4; ++i) {
        const int mrow = m0 + (wr << 6) + (i << 4) + (g << 2);
        #pragma unroll
        for (int j = 0; j < 4; ++j) {
            const int col = n0 + (wc << 6) + (j << 4) + r;
            if (EPI != 1 && col >= N) continue;
            #pragma unroll
            for (int q = 0; q < 4; ++q) {
                const float v = acc[i][j][q];
                const int mm = mrow + q;
                if (EPI == 0) {
                    out0[(size_t)mm * N + col] = v;
                } else if (EPI == 1) {
                    if (col < 256) out0[((size_t)mm << 8) + col] = v;
                    else out1b[((size_t)mm << 8) + (col - 256)] = f2b(silu_f(v));
                } else {
                    out0[(size_t)sidx * 2097152 +
                         ((size_t)(mm - rbase) << 7) + col] = v;
                }
            }
        }
    }
}

// ---------------------------------------------------------------------------
// Depthwise 3x3 conv (SAME) + bias + SiLU, batched; weights per stream.
// ---------------------------------------------------------------------------
__global__ __launch_bounds__(256) void dwconv_silu(
    const float* __restrict__ in,
    const float* __restrict__ w0, const float* __restrict__ b0,
    const float* __restrict__ w1, const float* __restrict__ b1,
    float* __restrict__ outf) {
    const int d = threadIdx.x;
    const int bp = blockIdx.x;            // [0, 32768)
    const int b = bp >> 12;               // [0, 8)
    const float* w = (b >= 4) ? w1 : w0;
    const float* bias = (b >= 4) ? b1 : b0;
    const int sp = bp & 4095;
    const int h = sp >> 6, wc = sp & 63;
    float acc = bias[d];
    #pragma unroll
    for (int kh = 0; kh < 3; ++kh) {
        const int hh = h + kh - 1;
        if (hh < 0 || hh >= 64) continue;
        #pragma unroll
        for (int kw = 0; kw < 3; ++kw) {
            const int ww = wc + kw - 1;
            if (ww < 0 || ww >= 64) continue;
            acc = fmaf(in[(size_t)(((b << 12) + (hh << 6) + ww)) * DDIM + d],
                       w[d * 9 + kh * 3 + kw], acc);
        }
    }
    outf[(size_t)bp * DDIM + d] = silu_f(acc);
}

// ---------------------------------------------------------------------------
// Scan phase A: per-chunk local scan from h=0. hend in fp16, cumd f32.
// blockIdx = bk*NCH + c, bk in [0,32) (batched). Layout [c][bk][d][n].
// ---------------------------------------------------------------------------
__global__ __launch_bounds__(256) void scanA(
    const float* __restrict__ xc, const float* __restrict__ proj,
    const float* __restrict__ Alogs, const float* __restrict__ dtw,
    const float* __restrict__ dtb,
    f16* __restrict__ hend, float* __restrict__ cumd) {
    const int d = threadIdx.x;
    const int blk = blockIdx.x;
    const int c = blk & (NCH - 1);
    const int bk = blk >> 7;              // [0, 32)
    const int k = bk & 3;
    const int b = bk >> 2;                // [0, 8)
    const int kd = (k << 8) + d;

    float a0;
    const bool geom = geom_check(Alogs, kd, a0);
    const float4 w0 = *(const float4*)(dtw + (size_t)kd * 8);
    const float4 w1 = *(const float4*)(dtw + (size_t)kd * 8 + 4);
    const float bias = dtb[kd];

    float h[16];
    #pragma unroll
    for (int n = 0; n < 16; ++n) h[n] = 0.f;
    float cum = 0.f;
    const int l0 = c * LCH;
    const int boff = b << 12;

    if (geom) {
        for (int t = 0; t < LCH; ++t) {
            const int p = perm_idx(k, l0 + t);
            const int bpp = boff + p;
            const float* pr0 = proj + (size_t)bpp * 160 + k * 40;
            const float delta = delta_of(pr0, w0, w1, bias);
            const float u = xc[(size_t)bpp * DDIM + d];
            const float du = delta * u;
            cum += delta;
            float dA[16];
            pow_geom(__expf(delta * a0), dA);
            #pragma unroll
            for (int n = 0; n < 16; ++n)
                h[n] = fmaf(dA[n], h[n], du * pr0[8 + n]);
        }
    } else {
        for (int t = 0; t < LCH; ++t) {
            const int p = perm_idx(k, l0 + t);
            const int bpp = boff + p;
            const float* pr0 = proj + (size_t)bpp * 160 + k * 40;
            const float delta = delta_of(pr0, w0, w1, bias);
            const float u = xc[(size_t)bpp * DDIM + d];
            const float du = delta * u;
            cum += delta;
            #pragma unroll
            for (int n = 0; n < 16; ++n) {
                const float an = -__expf(Alogs[(size_t)kd * 16 + n]);
                h[n] = fmaf(__expf(delta * an), h[n], du * pr0[8 + n]);
            }
        }
    }
    const size_t o = ((size_t)(c * 32 + bk) * DDIM + d) * 16;
    u16x8 r0, r1;
    #pragma unroll
    for (int n = 0; n < 8; ++n) {
        union { f16 h; unsigned short u; } v0, v1;
        v0.h = (f16)h[n]; v1.h = (f16)h[n + 8];
        r0[n] = v0.u; r1[n] = v1.u;
    }
    *(u16x8*)((unsigned short*)hend + o) = r0;
    *(u16x8*)((unsigned short*)hend + o + 8) = r1;
    cumd[(size_t)(c * 32 + bk) * DDIM + d] = cum;
}

// ---------------------------------------------------------------------------
// Scan phase B: inter-chunk recurrence over 131072 states, IN PLACE on the
// fp16 buffer (read hend[c], then overwrite slot c with H0[c]).
// ---------------------------------------------------------------------------
__global__ __launch_bounds__(256) void scanB(
    f16* __restrict__ hh, const float* __restrict__ cumd,
    const float* __restrict__ Alogs) {
    const int tid = blockIdx.x * 256 + threadIdx.x;   // [0, 131072)
    const int n = tid & 15;
    const int d = (tid >> 4) & 255;
    const int bk = tid >> 12;
    const int k = bk & 3;
    const float a = -__expf(Alogs[(size_t)(((k << 8) + d)) * 16 + n]);
    const int cdix = tid >> 4;                        // bk*256+d
    float H = 0.f;
    for (int c = 0; c < NCH; c += 4) {
        float tmp[4], cd[4];
        #pragma unroll
        for (int j = 0; j < 4; ++j) {
            tmp[j] = (float)hh[(size_t)(c + j) * 131072 + tid];
            cd[j] = cumd[(size_t)(c + j) * 8192 + cdix];
        }
        #pragma unroll
        for (int j = 0; j < 4; ++j) {
            hh[(size_t)(c + j) * 131072 + tid] = (f16)H;
            H = fmaf(__expf(cd[j] * a), H, tmp[j]);
        }
    }
}

// ---------------------------------------------------------------------------
// Scan phase C chunk worker: run one chunk of direction k from its true
// initial state (fp16 H0). EMIT=0: y -> ybuf[t][d]. EMIT=1: emit
// ybuf[31-t][d] + y to fp16 ysp plane at spatial position.
// ---------------------------------------------------------------------------
template <int EMIT>
__device__ __forceinline__ void scanC_chunk(
    const int k, const int chunk, const int b, const int d,
    const float* __restrict__ xc, const float* __restrict__ proj,
    const float* __restrict__ Alogs, const float* __restrict__ dtw,
    const float* __restrict__ dtb, const float* __restrict__ Dsv,
    const f16* __restrict__ H0, f16* __restrict__ ysp,
    float (*ybuf)[256], const size_t planeBase) {
    const int kd = (k << 8) + d;
    const int bk = (b << 2) + k;

    float a0;
    const bool geom = geom_check(Alogs, kd, a0);
    const float4 w0 = *(const float4*)(dtw + (size_t)kd * 8);
    const float4 w1 = *(const float4*)(dtw + (size_t)kd * 8 + 4);
    const float bias = dtb[kd];
    const float Dd = Dsv[kd];

    float h[16];
    const size_t ho = ((size_t)(chunk * 32 + bk) * DDIM + d) * 16;
    {
        const u16x8 r0 = *(const u16x8*)((const unsigned short*)H0 + ho);
        const u16x8 r1 = *(const u16x8*)((const unsigned short*)H0 + ho + 8);
        #pragma unroll
        for (int n = 0; n < 8; ++n) {
            union { unsigned short u; f16 h; } v0, v1;
            v0.u = r0[n]; v1.u = r1[n];
            h[n] = (float)v0.h; h[n + 8] = (float)v1.h;
        }
    }
    const int l0 = chunk * LCH;
    const int boff = b << 12;

    if (geom) {
        for (int t = 0; t < LCH; ++t) {
            const int p = perm_idx(k, l0 + t);
            const int bpp = boff + p;
            const float* pr0 = proj + (size_t)bpp * 160 + k * 40;
            const float delta = delta_of(pr0, w0, w1, bias);
            const float u = xc[(size_t)bpp * DDIM + d];
            const float du = delta * u;
            float dA[16];
            pow_geom(__expf(delta * a0), dA);
            const float4 Ba = *(const float4*)(pr0 + 8);
            const float4 Bb = *(const float4*)(pr0 + 12);
            const float4 Bc = *(const float4*)(pr0 + 16);
            const float4 Bd = *(const float4*)(pr0 + 20);
            const float4 Ca = *(const float4*)(pr0 + 24);
            const float4 Cb = *(const float4*)(pr0 + 28);
            const float4 Cc = *(const float4*)(pr0 + 32);
            const float4 Cd = *(const float4*)(pr0 + 36);
            const float Bv[16] = {Ba.x,Ba.y,Ba.z,Ba.w, Bb.x,Bb.y,Bb.z,Bb.w,
                                  Bc.x,Bc.y,Bc.z,Bc.w, Bd.x,Bd.y,Bd.z,Bd.w};
            const float Cv[16] = {Ca.x,Ca.y,Ca.z,Ca.w, Cb.x,Cb.y,Cb.z,Cb.w,
                                  Cc.x,Cc.y,Cc.z,Cc.w, Cd.x,Cd.y,Cd.z,Cd.w};
            float y = 0.f;
            #pragma unroll
            for (int n = 0; n < 16; ++n) {
                h[n] = fmaf(dA[n], h[n], du * Bv[n]);
                y = fmaf(h[n], Cv[n], y);
            }
            y = fmaf(Dd, u, y);
            if (EMIT == 0) ybuf[t][d] = y;
            else ysp[planeBase + (size_t)p * DDIM + d] =
                     (f16)(y + ybuf[31 - t][d]);
        }
    } else {
        for (int t = 0; t < LCH; ++t) {
            const int p = perm_idx(k, l0 + t);
            const int bpp = boff + p;
            const float* pr0 = proj + (size_t)bpp * 160 + k * 40;
            const float delta = delta_of(pr0, w0, w1, bias);
            const float u = xc[(size_t)bpp * DDIM + d];
            const float du = delta * u;
            float y = 0.f;
            #pragma unroll
            for (int n = 0; n < 16; ++n) {
                const float an = -__expf(Alogs[(size_t)kd * 16 + n]);
                h[n] = fmaf(__expf(delta * an), h[n], du * pr0[8 + n]);
                y = fmaf(h[n], pr0[24 + n], y);
            }
            y = fmaf(Dd, u, y);
            if (EMIT == 0) ybuf[t][d] = y;
            else ysp[planeBase + (size_t)p * DDIM + d] =
                     (f16)(y + ybuf[31 - t][d]);
        }
    }
}

// ---------------------------------------------------------------------------
// Scan phase C, pair-fused: (k=pair, chunk c) then (k=pair+2, NCH-1-c);
// same 32-position window, pair-sum emitted to 16 fp16 planes.
// blockIdx = (b*2+pair)*NCH + c, b in [0,8).
// ---------------------------------------------------------------------------
__global__ __launch_bounds__(256) void scanC2(
    const float* __restrict__ xc, const float* __restrict__ proj,
    const float* __restrict__ Alogs, const float* __restrict__ dtw,
    const float* __restrict__ dtb, const float* __restrict__ Dsv,
    const f16* __restrict__ H0, f16* __restrict__ ysp) {
    __shared__ float ybuf[LCH][256];
    const int d = threadIdx.x;
    const int blk = blockIdx.x;
    const int c = blk & (NCH - 1);
    const int bp2 = blk >> 7;             // [0, 16)
    const int pair = bp2 & 1;
    const int b = bp2 >> 1;               // [0, 8)
    const size_t planeBase = (size_t)bp2 << 20;
    scanC_chunk<0>(pair, c, b, d, xc, proj, Alogs, dtw, dtb, Dsv, H0,
                   ysp, ybuf, planeBase);
    scanC_chunk<1>(pair + 2, NCH - 1 - c, b, d, xc, proj, Alogs, dtw, dtb,
                   Dsv, H0, ysp, ybuf, planeBase);
}

// ---------------------------------------------------------------------------
// Merge 2 pair-planes (fp16) + LayerNorm(D) + gate with bf16 z -> bf16 yz.
// ---------------------------------------------------------------------------
__global__ __launch_bounds__(256) void merge_ln(
    const f16* __restrict__ ysp, const unsigned short* __restrict__ z,
    const float* __restrict__ lnw, const float* __restrict__ lnb,
    unsigned short* __restrict__ yzb) {
    const int d = threadIdx.x;
    const int bp = blockIdx.x;            // [0, 32768)
    const int b = bp >> 12;               // [0, 8)
    const int p = bp & 4095;
    const float v =
        (float)ysp[(((size_t)(b << 1)) << 20) + (size_t)p * DDIM + d] +
        (float)ysp[(((size_t)(b << 1) + 1) << 20) + (size_t)p * DDIM + d];

    __shared__ float red[4];
    float s = v;
    #pragma unroll
    for (int o = 32; o > 0; o >>= 1) s += __shfl_xor(s, o);
    const int wave = threadIdx.x >> 6;
    if ((threadIdx.x & 63) == 0) red[wave] = s;
    __syncthreads();
    const float mu = (red[0] + red[1] + red[2] + red[3]) * (1.f / 256.f);
    __syncthreads();
    const float dv = v - mu;
    float s2 = dv * dv;
    #pragma unroll
    for (int o = 32; o > 0; o >>= 1) s2 += __shfl_xor(s2, o);
    if ((threadIdx.x & 63) == 0) red[wave] = s2;
    __syncthreads();
    const float var = (red[0] + red[1] + red[2] + red[3]) * (1.f / 256.f);
    const float y = dv * rsqrtf(var + 1e-5f) * lnw[d] + lnb[d];
    yzb[(size_t)bp * DDIM + d] = f2b(y * b2f(z[(size_t)bp * DDIM + d]));
}

// ---------------------------------------------------------------------------
extern "C" void kernel_launch(void* const* d_in, const int* in_sizes, int n_in,
                              void* d_out, int out_size, void* d_ws, size_t ws_size,
                              hipStream_t stream) {
    const float* xin0  = (const float*)d_in[0];
    const float* xin1  = (const float*)d_in[1];
    const float* inw0  = (const float*)d_in[2];
    const float* inw1  = (const float*)d_in[3];
    const float* convw0 = (const float*)d_in[4];
    const float* convb0 = (const float*)d_in[5];
    const float* convw1 = (const float*)d_in[6];
    const float* convb1 = (const float*)d_in[7];
    const float* xpw   = (const float*)d_in[8];
    const float* dtw   = (const float*)d_in[9];
    const float* dtb   = (const float*)d_in[10];
    const float* Alogs = (const float*)d_in[11];
    const float* Dsv   = (const float*)d_in[12];
    const float* lnw   = (const float*)d_in[13];
    const float* lnb   = (const float*)d_in[14];
    const float* outw0 = (const float*)d_in[15];
    const float* outw1 = (const float*)d_in[16];

    float* ws = (float*)d_ws;
    // layout (float offsets), total 35,770,368 floats = 143.1 MB:
    float* xc_raw  = ws + 0;             // 8,388,608  in_proj xc (dead after conv)
    f16*   ysp     = (f16*)(ws + 0);     //            16 fp16 planes (scanC->merge)
    unsigned short* zbuf = (unsigned short*)(ws + 8388608);  // 8.39M bf16
    float* xc_conv = ws + 12582912;      // 8,388,608  conv out (scan input)
    float* proj    = ws + 20971520;      // 5,242,880  x_proj out
    unsigned short* yzbf = (unsigned short*)(ws + 20971520); // after scanC
    f16*   hendH0  = (f16*)(ws + 26214400); // 16.78M fp16 (in-place hend->H0)
    float* cumd    = ws + 34603008;      // 1,048,576
    unsigned short* wreg = (unsigned short*)(ws + 35651584); // 237,568 bf16
    unsigned short* wbf_in0  = wreg + 0;
    unsigned short* wbf_in1  = wreg + 65536;
    unsigned short* wbf_xp   = wreg + 131072;
    unsigned short* wbf_out0 = wreg + 172032;
    unsigned short* wbf_out1 = wreg + 204800;
    float* outp = (float*)d_out;

    // 1: all weight conversions (one launch)
    cvt_all<<<116, 256, 0, stream>>>(inw0, inw1, xpw, outw0, outw1, wreg);
    // 2: in_proj, both streams (M=32768, N=512, K=128), fp32-A staging
    gemm_bf<1, true><<<dim3(4, 256), 256, 0, stream>>>(
        nullptr, xin0, xin1, wbf_in0, wbf_in1, xc_raw, zbuf, 512, 128, 16384);
    // 3: depthwise conv + silu (both streams)
    dwconv_silu<<<32768, 256, 0, stream>>>(xc_raw, convw0, convb0,
                                           convw1, convb1, xc_conv);
    // 4: x_proj (M=32768, N=160, K=256), fp32-A staging, shared W
    gemm_bf<0, true><<<dim3(2, 256), 256, 0, stream>>>(
        nullptr, xc_conv, xc_conv, wbf_xp, wbf_xp, proj, nullptr,
        160, 256, 1 << 30);
    // 5-7: chunked selective scan (both streams, fp16 state)
    scanA<<<32 * NCH, 256, 0, stream>>>(xc_conv, proj, Alogs, dtw, dtb,
                                        hendH0, cumd);
    scanB<<<512, 256, 0, stream>>>(hendH0, cumd, Alogs);
    scanC2<<<16 * NCH, 256, 0, stream>>>(xc_conv, proj, Alogs, dtw, dtb,
                                         Dsv, hendH0, ysp);
    // 8: merge pair-planes + LN + gate -> bf16
    merge_ln<<<32768, 256, 0, stream>>>(ysp, zbuf, lnw, lnb, yzbf);
    // 9: out_proj (M=32768, N=128, K=256), per-stream W and output offset
    gemm_bf<2, false><<<dim3(1, 256), 256, 0, stream>>>(
        yzbf, nullptr, nullptr, wbf_out0, wbf_out1, outp, nullptr,
        128, 256, 16384);
}